// Round 6
// baseline (155.510 us; speedup 1.0000x reference)
//
#include <hip/hip_runtime.h>

typedef _Float16 f16;
typedef _Float16 f16x2 __attribute__((ext_vector_type(2)));
typedef _Float16 f16x4 __attribute__((ext_vector_type(4)));
typedef _Float16 f16x8 __attribute__((ext_vector_type(8)));
typedef float    f32x4 __attribute__((ext_vector_type(4)));
typedef unsigned int u32;
typedef u32      u32x2 __attribute__((ext_vector_type(2)));
typedef u32      u32x4 __attribute__((ext_vector_type(4)));

#define MFMA32(a, b, c) __builtin_amdgcn_mfma_f32_16x16x32_f16((a), (b), (c), 0, 0, 0)
// NOTE: legacy K=16 intrinsic has NO underscore before f16 on gfx950
#define MFMA16(a, b, c) __builtin_amdgcn_mfma_f32_16x16x16f16((a), (b), (c), 0, 0, 0)

#define TILES 4   // batch-tiles (of 16) per block; grid = 8192/TILES = 2048

__device__ __forceinline__ float leaky(float x) {
    return fmaf(0.4f, __builtin_fabsf(x), 0.6f * x);
}
__device__ __forceinline__ u32 pkrtz(float a, float b) {
    return __builtin_bit_cast(u32, __builtin_amdgcn_cvt_pkrtz(a, b));
}
// leaky(x) == max(x, 0.2x): x>=0 -> x exact; x<0 -> 0.2x (f16 rne), identical
// rounding to the previous min/max/fma form but 3 ops per pair instead of 4.
__device__ __forceinline__ u32 lk_pk2(float a, float b) {
    f16x2 v = __builtin_bit_cast(f16x2, __builtin_amdgcn_cvt_pkrtz(a, b));
    f16x2 s = v * (f16x2){(f16)0.2f, (f16)0.2f};
    f16x2 r = __builtin_elementwise_max(v, s);
    return __builtin_bit_cast(u32, r);
}
__device__ __forceinline__ f16x4 lk_pk4(const f32x4 z) {
    return __builtin_bit_cast(f16x4, (u32x2){ lk_pk2(z[0], z[1]), lk_pk2(z[2], z[3]) });
}
__device__ __forceinline__ f16x4 pk4(const f32x4 z) {
    return __builtin_bit_cast(f16x4, (u32x2){ pkrtz(z[0], z[1]), pkrtz(z[2], z[3]) });
}
__device__ __forceinline__ void st_lk4(void* p, const f32x4 z) {
    *(u32x2*)p = (u32x2){ lk_pk2(z[0], z[1]), lk_pk2(z[2], z[3]) };
}

// ---------------------------------------------------------------------------
// Prepack: f16 MFMA fragments in d_ws (unchanged).
// ---------------------------------------------------------------------------
__global__ void disc_prepack(const float* __restrict__ Wp1, const float* __restrict__ Wp2,
                             const float* __restrict__ Wn1, const float* __restrict__ Wn2,
                             const float* __restrict__ Wl1, const float* __restrict__ Wl2,
                             f16* __restrict__ ws)
{
    int idx = blockIdx.x * 256 + threadIdx.x;
    if (idx >= 84 * 512 + 24 * 256) return;
    float v = 0.0f;
    if (idx < 84 * 512) {
        int f = idx >> 9, r = idx & 511;
        int lane = r >> 3, e = r & 7;
        int m15 = lane & 15, h = lane >> 4;
        if (f < 64) {
            int mt4 = f >> 4, ks4 = f & 15;
            int k = ks4 * 32 + h * 8 + e;
            v = Wl1[k * 64 + mt4 * 16 + m15];
        } else if (f < 72) {
            int q = f - 64, c = q >> 2, mt = q & 3;
            const float* W1 = c ? Wn1 : Wp1;
            v = (lane < 16) ? W1[e * 64 + mt * 16 + m15] : 0.0f;
        } else if (f < 80) {
            int q = f - 72, c = q >> 2, nt2 = (q >> 1) & 1, ks2 = q & 1;
            const float* W2 = c ? Wn2 : Wp2;
            int k = ks2 * 32 + h * 8 + e;
            v = W2[k * 32 + nt2 * 16 + m15];
        } else {
            int q = f - 80, ms5 = q >> 1, ks5 = q & 1;
            int k = ks5 * 32 + h * 8 + e;
            v = Wl2[k * 32 + ms5 * 16 + m15];
        }
    } else {
        int r2 = idx - 84 * 512;
        int f2 = r2 >> 8, rr = r2 & 255;
        int lane = rr >> 2, e = rr & 3;
        int m15 = lane & 15, h = lane >> 4;
        if (f2 < 16) {
            int c = f2 >> 3, kb = (f2 >> 1) & 3, nt = f2 & 1;
            const float* W2 = c ? Wn2 : Wp2;
            v = W2[(kb * 16 + h * 4 + e) * 32 + nt * 16 + m15];
        } else {
            int q = f2 - 16, kb = q >> 1, nt = q & 1;
            v = Wl2[(kb * 16 + h * 4 + e) * 32 + nt * 16 + m15];
        }
    }
    ws[idx] = (f16)v;
}

// ---------------------------------------------------------------------------
// R19: BARRIER-FREE single-wave blocks.
//   R13-R18 POST-MORTEM: dur pinned at 54-62us across occupancy 5-11
//   waves/CU and ILP 2-4 streams. Invariants: VALU busy-time ~18-24us,
//   MFMA ~13-15us, stall ~20us. The 2-wave barrier-coupled block forces
//   lockstep (2 syncthreads + LDS exchange per tile), so co-resident waves
//   stall on the SAME points instead of interleaving.
//   Fix: block = ONE wave (64 thr) doing BOTH channels sequentially
//   (two compile-time register sets, inlined worker called twice), h1
//   accumulated across channels in registers -> exchange, both barriers,
//   and wave0-only tail divergence all gone. Albuf/xbuf time-shared
//   between channels (sequential within the wave, compiler waitcnts).
//   8 independent waves/CU interleave freely. Plus lk_pk2 = max(x,0.2x)
//   (3 ops vs 4, bit-identical).
// LDS: Albuf 2048 + xbuf 8192 = 10240/block.
// ---------------------------------------------------------------------------
__global__ __launch_bounds__(64, 2) void disc_main(
    const float* __restrict__ adj,
    const float* __restrict__ bp1, const float* __restrict__ bp2,
    const float* __restrict__ bn1, const float* __restrict__ bn2,
    const float* __restrict__ bl1, const float* __restrict__ bl2,
    const float* __restrict__ bl3, const float* __restrict__ Wl3,
    const f16* __restrict__ ws, float* __restrict__ out)
{
    extern __shared__ char smem[];
    const int lane = threadIdx.x;   // block = one wave
    const int h    = lane >> 4;
    const int m15  = lane & 15;
    const int i7   = lane & 7;
    const int r8   = m15 >> 3;

    const f16x8* wsf = (const f16x8*)ws;
    const f16x4* wsq = (const f16x4*)(ws + 84 * 512);   // 16x16x16 B-frags

    // ---- channel 0 (pos) weights/biases ----
    const f16x8* w1pp = wsf + 64 * 64 + lane;
    f16x8 Wp10 = w1pp[0], Wp11 = w1pp[64], Wp12 = w1pp[128], Wp13 = w1pp[192];
    const f16x4* w2pp = wsq + lane;
    f16x4 Kp00 = w2pp[0],   Kp01 = w2pp[64];
    f16x4 Kp10 = w2pp[128], Kp11 = w2pp[192];
    f16x4 Kp20 = w2pp[256], Kp21 = w2pp[320];
    f16x4 Kp30 = w2pp[384], Kp31 = w2pp[448];
    const f32x4* b1pp = (const f32x4*)bp1;
    f32x4 Bp10 = b1pp[h], Bp11 = b1pp[4 + h], Bp12 = b1pp[8 + h], Bp13 = b1pp[12 + h];
    const f32x4* b2pp = (const f32x4*)bp2;
    f32x4 Bp20 = b2pp[h], Bp21 = b2pp[4 + h];

    // ---- channel 1 (neg) weights/biases ----
    const f16x8* w1pn = wsf + (64 + 4) * 64 + lane;
    f16x8 Wn10 = w1pn[0], Wn11 = w1pn[64], Wn12 = w1pn[128], Wn13 = w1pn[192];
    const f16x4* w2pn = wsq + 8 * 64 + lane;
    f16x4 Kn00 = w2pn[0],   Kn01 = w2pn[64];
    f16x4 Kn10 = w2pn[128], Kn11 = w2pn[192];
    f16x4 Kn20 = w2pn[256], Kn21 = w2pn[320];
    f16x4 Kn30 = w2pn[384], Kn31 = w2pn[448];
    const f32x4* b1pn = (const f32x4*)bn1;
    f32x4 Bn10 = b1pn[h], Bn11 = b1pn[4 + h], Bn12 = b1pn[8 + h], Bn13 = b1pn[12 + h];
    const f32x4* b2pn = (const f32x4*)bn2;
    f32x4 Bn20 = b2pn[h], Bn21 = b2pn[4 + h];

    // ---- shared tail / h1 bias ----
    f32x4 bl1v0 = ((const f32x4*)bl1)[h],      bl1v1 = ((const f32x4*)bl1)[4 + h];
    f32x4 bl1v2 = ((const f32x4*)bl1)[8 + h],  bl1v3 = ((const f32x4*)bl1)[12 + h];
    const f16x4* wl2p = wsq + 16 * 64 + lane;
    f16x4 l200 = wl2p[0],   l201 = wl2p[64];
    f16x4 l210 = wl2p[128], l211 = wl2p[192];
    f16x4 l220 = wl2p[256], l221 = wl2p[320];
    f16x4 l230 = wl2p[384], l231 = wl2p[448];
    float c0 = bl2[m15], c1 = bl2[m15 + 16];
    float w30 = Wl3[m15], w31 = Wl3[m15 + 16];
    const float bl3s = bl3[0];

    char* Albuf = smem;               // 2048 B, time-shared between channels
    char* xbuf  = smem + 2048;        // 8192 B, time-shared between channels

    const int rxor = ((m15 >> 1) & 3) << 4;
    const bool bsel = ((h >> 1) == r8);    // s3 B-frag block-diag gate
    const int  hlow = h & 1;               // s3 B-frag row-half select
    f32x4 zero4 = {0.0f, 0.0f, 0.0f, 0.0f};
    f16x4 zf4 = {};

    // per-channel worker: Phase A (load+normalize+stage), B (fused GCN),
    // C (h1 partial accumulate). Weights passed by value = compile-time
    // register-set selection; c only appears in ADDRESSES.
    auto run_channel = [&](long b0, int c,
        f16x8 W10, f16x8 W11, f16x8 W12, f16x8 W13,
        f16x4 K00, f16x4 K01, f16x4 K10, f16x4 K11,
        f16x4 K20, f16x4 K21, f16x4 K30, f16x4 K31,
        f32x4 B10, f32x4 B11, f32x4 B12, f32x4 B13,
        f32x4 B20, f32x4 B21,
        f32x4& a40, f32x4& a41, f32x4& a42, f32x4& a43)
    {
        // ---- Phase A: load 128 rows (2 per lane), normalize, stage ----
        {
            const f32x4* rp0 = (const f32x4*)(adj + (b0 + (lane >> 3)) * 128 + c * 64 + (lane & 7) * 8);
            const f32x4* rp1 = (const f32x4*)(adj + (b0 + 8 + (lane >> 3)) * 128 + c * 64 + (lane & 7) * 8);
            f32x4 a0 = rp0[0], a1 = rp0[1];
            f32x4 b0v = rp1[0], b1v = rp1[1];
            {
                float s = ((a0[0] + a0[1]) + (a0[2] + a0[3])) + ((a1[0] + a1[1]) + (a1[2] + a1[3]));
                float rv = (s > 0.0f) ? __builtin_amdgcn_rcpf(s) : 0.0f;
                u32x4 row = { pkrtz(a0[0] * rv, a0[1] * rv), pkrtz(a0[2] * rv, a0[3] * rv),
                              pkrtz(a1[0] * rv, a1[1] * rv), pkrtz(a1[2] * rv, a1[3] * rv) };
                *(u32x4*)(Albuf + lane * 16) = row;
            }
            {
                float s = ((b0v[0] + b0v[1]) + (b0v[2] + b0v[3])) + ((b1v[0] + b1v[1]) + (b1v[2] + b1v[3]));
                float rv = (s > 0.0f) ? __builtin_amdgcn_rcpf(s) : 0.0f;
                u32x4 row = { pkrtz(b0v[0] * rv, b0v[1] * rv), pkrtz(b0v[2] * rv, b0v[3] * rv),
                              pkrtz(b1v[0] * rv, b1v[1] * rv), pkrtz(b1v[2] * rv, b1v[3] * rv) };
                *(u32x4*)(Albuf + (64 + lane) * 16) = row;
            }
        }

        // ---- Phase B: fused GCN over t = 0..7 (full unroll, const t) ----
        #pragma unroll
        for (int t = 0; t < 8; ++t) {
            f16x8 arow = *(const f16x8*)(Albuf + (((2 * t + r8) * 8 + i7) << 4));

            // s1: z^T = W1^T @ A^T + b1 (16x16x32, K=8 pad)
            f32x4 z0 = MFMA32(W10, arow, B10);
            f32x4 z1 = MFMA32(W11, arow, B11);
            f32x4 z2 = MFMA32(W12, arow, B12);
            f32x4 z3 = MFMA32(W13, arow, B13);

            // s1 -> s2: register pack+leaky (packed f16 math)
            f16x4 x0 = lk_pk4(z0), x1 = lk_pk4(z1), x2 = lk_pk4(z2), x3 = lk_pk4(z3);

            // s2: y_nt = sum_kb x1 @ W2 (two 4-chains of 16x16x16)
            f32x4 y0 = MFMA16(x0, K00, zero4);
            f32x4 y1 = MFMA16(x0, K01, zero4);
            y0 = MFMA16(x1, K10, y0);
            y1 = MFMA16(x1, K11, y1);
            y0 = MFMA16(x2, K20, y0);
            y1 = MFMA16(x2, K21, y1);
            y0 = MFMA16(x3, K30, y0);
            y1 = MFMA16(x3, K31, y1);

            // s2 -> s3: register pkrtz; B-frag from arow select (block-diag)
            f16x4 pa0 = pk4(y0), pa1 = pk4(y1);
            u32x4 ar = __builtin_bit_cast(u32x4, arow);
            f16x4 halfa = __builtin_bit_cast(f16x4,
                hlow ? (u32x2){ar[2], ar[3]} : (u32x2){ar[0], ar[1]});
            f16x4 bfra = bsel ? halfa : zf4;

            // s3: x2^T = y^T @ BD_A^T + b2 (16x16x16, K=16 exact)
            f32x4 x2a = MFMA16(pa0, bfra, B20);
            f32x4 x2b = MFMA16(pa1, bfra, B21);

            // leaky+pack + swizzled xbuf writes; slot = i7, n = 2t+r8
            const int lga = h >> 1;
            const int lgb = lga ^ 2;
            char* fb = xbuf + (i7 << 10);
            int wx = ((t & 3) ^ i7) << 4;
            int basew = ((2 * t + r8) << 6) + ((h & 1) << 3);
            st_lk4(fb + ((basew + lga * 16) ^ wx), x2a);
            st_lk4(fb + ((basew + lgb * 16) ^ wx), x2b);
        }

        // ---- Phase C: h1 partial += Wl1^T[k-half c] @ x^T (K=256) ----
        __builtin_amdgcn_s_setprio(1);
        #pragma unroll
        for (int k8 = 0; k8 < 8; ++k8) {
            int xr = rxor ^ (k8 << 4);
            f16x8 xf = *(const f16x8*)(xbuf + (k8 << 10) + ((m15 * 64 + h * 16) ^ xr));
            const f16x8* wl = wsf + (c * 8 + k8) * 64 + lane;
            a40 = MFMA32(wl[0],    xf, a40);
            a41 = MFMA32(wl[1024], xf, a41);
            a42 = MFMA32(wl[2048], xf, a42);
            a43 = MFMA32(wl[3072], xf, a43);
        }
        __builtin_amdgcn_s_setprio(0);
    };

    long b0 = (long)blockIdx.x * (16 * TILES);

    #pragma unroll 1
    for (int it = 0; it < TILES; ++it, b0 += 16) {
        // h1 accumulator, bias-seeded once; both channels accumulate into it
        f32x4 a40 = bl1v0, a41 = bl1v1, a42 = bl1v2, a43 = bl1v3;

        run_channel(b0, 0,
                    Wp10, Wp11, Wp12, Wp13,
                    Kp00, Kp01, Kp10, Kp11, Kp20, Kp21, Kp30, Kp31,
                    Bp10, Bp11, Bp12, Bp13, Bp20, Bp21,
                    a40, a41, a42, a43);
        run_channel(b0, 1,
                    Wn10, Wn11, Wn12, Wn13,
                    Kn00, Kn01, Kn10, Kn11, Kn20, Kn21, Kn30, Kn31,
                    Bn10, Bn11, Bn12, Bn13, Bn20, Bn21,
                    a40, a41, a42, a43);

        // ---- Phase D: register pack+leaky of h1 (A-frags for E) ----
        f16x4 pd0 = lk_pk4(a40), pd1 = lk_pk4(a41);
        f16x4 pd2 = lk_pk4(a42), pd3 = lk_pk4(a43);

        // ---- Phase E: h2 = h1 @ Wl2 + bl2 (4-chain 16x16x16 per nt) ----
        f32x4 a50 = {c0, c0, c0, c0};
        f32x4 a51 = {c1, c1, c1, c1};
        a50 = MFMA16(pd0, l200, a50);
        a51 = MFMA16(pd0, l201, a51);
        a50 = MFMA16(pd1, l210, a50);
        a51 = MFMA16(pd1, l211, a51);
        a50 = MFMA16(pd2, l220, a50);
        a51 = MFMA16(pd2, l221, a51);
        a50 = MFMA16(pd3, l230, a50);
        a51 = MFMA16(pd3, l231, a51);

        // ---- Phase F: out[b=4h+r] = sum_l2 leaky(h2) Wl3 + bl3 ----
        #pragma unroll
        for (int r = 0; r < 4; ++r) {
            float acc = leaky(a50[r]) * w30 + leaky(a51[r]) * w31;
            acc += __shfl_xor(acc, 1);
            acc += __shfl_xor(acc, 2);
            acc += __shfl_xor(acc, 4);
            acc += __shfl_xor(acc, 8);
            if (m15 == 0) out[b0 + h * 4 + r] = acc + bl3s;
        }
    }
}

extern "C" void kernel_launch(void* const* d_in, const int* in_sizes, int n_in,
                              void* d_out, int out_size, void* d_ws, size_t ws_size,
                              hipStream_t stream)
{
    const float* adj  = (const float*)d_in[0];
    const float* Wp1  = (const float*)d_in[1];
    const float* bp1  = (const float*)d_in[2];
    const float* Wp2  = (const float*)d_in[3];
    const float* bp2  = (const float*)d_in[4];
    const float* Wn1  = (const float*)d_in[5];
    const float* bn1  = (const float*)d_in[6];
    const float* Wn2  = (const float*)d_in[7];
    const float* bn2  = (const float*)d_in[8];
    const float* Wl1  = (const float*)d_in[9];
    const float* bl1  = (const float*)d_in[10];
    const float* Wl2  = (const float*)d_in[11];
    const float* bl2  = (const float*)d_in[12];
    const float* Wl3  = (const float*)d_in[13];
    const float* bl3  = (const float*)d_in[14];
    f16* ws = (f16*)d_ws;
    float* out = (float*)d_out;

    // 84*512 + 24*256 = 49152 f16; 192 blocks x 256 threads
    hipLaunchKernelGGL(disc_prepack, dim3(192), dim3(256), 0, stream,
                       Wp1, Wp2, Wn1, Wn2, Wl1, Wl2, ws);

    const int ldsBytes = 10240;  // Albuf 2K + xbuf 8K, channel time-shared
    hipFuncSetAttribute(reinterpret_cast<const void*>(disc_main),
                        hipFuncAttributeMaxDynamicSharedMemorySize, ldsBytes);
    hipLaunchKernelGGL(disc_main, dim3(8192 / TILES), dim3(64), ldsBytes, stream,
                       adj, bp1, bp2, bn1, bn2, bl1, bl2, bl3, Wl3, ws, out);
}

// Round 7
// 53.745 us; speedup vs baseline: 2.8935x; 2.8935x over previous
//
#include <hip/hip_runtime.h>

typedef _Float16 f16;
typedef _Float16 f16x2 __attribute__((ext_vector_type(2)));
typedef _Float16 f16x4 __attribute__((ext_vector_type(4)));
typedef _Float16 f16x8 __attribute__((ext_vector_type(8)));
typedef float    f32x4 __attribute__((ext_vector_type(4)));
typedef unsigned int u32;
typedef u32      u32x2 __attribute__((ext_vector_type(2)));
typedef u32      u32x4 __attribute__((ext_vector_type(4)));

#define MFMA32(a, b, c) __builtin_amdgcn_mfma_f32_16x16x32_f16((a), (b), (c), 0, 0, 0)
// NOTE: legacy K=16 intrinsic has NO underscore before f16 on gfx950
#define MFMA16(a, b, c) __builtin_amdgcn_mfma_f32_16x16x16f16((a), (b), (c), 0, 0, 0)

#define TILES 4   // batch-tiles per WAVE; grid = 8192/(2*TILES) = 1024 blocks

__device__ __forceinline__ float leaky(float x) {
    return fmaf(0.4f, __builtin_fabsf(x), 0.6f * x);
}
__device__ __forceinline__ u32 pkrtz(float a, float b) {
    return __builtin_bit_cast(u32, __builtin_amdgcn_cvt_pkrtz(a, b));
}
// leaky(x) == max(x, 0.2x): x>=0 -> x exact; x<0 -> 0.2x (f16 rne). 3 ops/pair.
__device__ __forceinline__ u32 lk_pk2(float a, float b) {
    f16x2 v = __builtin_bit_cast(f16x2, __builtin_amdgcn_cvt_pkrtz(a, b));
    f16x2 s = v * (f16x2){(f16)0.2f, (f16)0.2f};
    f16x2 r = __builtin_elementwise_max(v, s);
    return __builtin_bit_cast(u32, r);
}
__device__ __forceinline__ f16x4 lk_pk4(const f32x4 z) {
    return __builtin_bit_cast(f16x4, (u32x2){ lk_pk2(z[0], z[1]), lk_pk2(z[2], z[3]) });
}
__device__ __forceinline__ f16x4 pk4(const f32x4 z) {
    return __builtin_bit_cast(f16x4, (u32x2){ pkrtz(z[0], z[1]), pkrtz(z[2], z[3]) });
}
__device__ __forceinline__ void st_lk4(void* p, const f32x4 z) {
    *(u32x2*)p = (u32x2){ lk_pk2(z[0], z[1]), lk_pk2(z[2], z[3]) };
}

// ---------------------------------------------------------------------------
// Prepack: f16 MFMA fragments in d_ws (unchanged).
// ---------------------------------------------------------------------------
__global__ void disc_prepack(const float* __restrict__ Wp1, const float* __restrict__ Wp2,
                             const float* __restrict__ Wn1, const float* __restrict__ Wn2,
                             const float* __restrict__ Wl1, const float* __restrict__ Wl2,
                             f16* __restrict__ ws)
{
    int idx = blockIdx.x * 256 + threadIdx.x;
    if (idx >= 84 * 512 + 24 * 256) return;
    float v = 0.0f;
    if (idx < 84 * 512) {
        int f = idx >> 9, r = idx & 511;
        int lane = r >> 3, e = r & 7;
        int m15 = lane & 15, h = lane >> 4;
        if (f < 64) {
            int mt4 = f >> 4, ks4 = f & 15;
            int k = ks4 * 32 + h * 8 + e;
            v = Wl1[k * 64 + mt4 * 16 + m15];
        } else if (f < 72) {
            int q = f - 64, c = q >> 2, mt = q & 3;
            const float* W1 = c ? Wn1 : Wp1;
            v = (lane < 16) ? W1[e * 64 + mt * 16 + m15] : 0.0f;
        } else if (f < 80) {
            int q = f - 72, c = q >> 2, nt2 = (q >> 1) & 1, ks2 = q & 1;
            const float* W2 = c ? Wn2 : Wp2;
            int k = ks2 * 32 + h * 8 + e;
            v = W2[k * 32 + nt2 * 16 + m15];
        } else {
            int q = f - 80, ms5 = q >> 1, ks5 = q & 1;
            int k = ks5 * 32 + h * 8 + e;
            v = Wl2[k * 32 + ms5 * 16 + m15];
        }
    } else {
        int r2 = idx - 84 * 512;
        int f2 = r2 >> 8, rr = r2 & 255;
        int lane = rr >> 2, e = rr & 3;
        int m15 = lane & 15, h = lane >> 4;
        if (f2 < 16) {
            int c = f2 >> 3, kb = (f2 >> 1) & 3, nt = f2 & 1;
            const float* W2 = c ? Wn2 : Wp2;
            v = W2[(kb * 16 + h * 4 + e) * 32 + nt * 16 + m15];
        } else {
            int q = f2 - 16, kb = q >> 1, nt = q & 1;
            v = Wl2[(kb * 16 + h * 4 + e) * 32 + nt * 16 + m15];
        }
    }
    ws[idx] = (f16)v;
}

// ---------------------------------------------------------------------------
// R20: barrier-free independent waves, spill-proofed.
//   R19 POST-MORTEM: the barrier-free single-wave structure was correct but
//   spilled (both channel weight sets live = ~230+ regs; (64,2) bound gave
//   a 128 cap -> 122MB scratch). Fixes:
//   (1) Only ONE channel weight set live at a time (56 regs), reloaded per
//       channel-phase (14 VMEM, L1-hot: every wave reads the same addrs;
//       issued before Phase A's VALU so latency hides).
//   (2) Two INDEPENDENT waves per 128-thr block under (128,2) -- the
//       config with a PROVEN 256-reg cap and no spill (R13-R18). Zero
//       __syncthreads in the kernel; each wave owns a private 10240B LDS
//       area and its own TILES=4 batch range.
//   (3) grid 1024 -> 4 blocks/CU = 8 independent waves/CU = 2/SIMD (the
//       VGPR-allowed residency); scheduler interleaves one wave's MFMA
//       phases into another's VALU/LDS stalls -- no common stall points.
// LDS: 2 x (Albuf 2048 + xbuf 8192) = 20480/block.
// ---------------------------------------------------------------------------
__global__ __launch_bounds__(128, 2) void disc_main(
    const float* __restrict__ adj,
    const float* __restrict__ bp1, const float* __restrict__ bp2,
    const float* __restrict__ bn1, const float* __restrict__ bn2,
    const float* __restrict__ bl1, const float* __restrict__ bl2,
    const float* __restrict__ bl3, const float* __restrict__ Wl3,
    const f16* __restrict__ ws, float* __restrict__ out)
{
    extern __shared__ char smem[];
    const int tid  = threadIdx.x;
    const int lane = tid & 63;
    const int wid  = tid >> 6;     // independent wave; NO barriers anywhere
    const int h    = lane >> 4;
    const int m15  = lane & 15;
    const int i7   = lane & 7;
    const int r8   = m15 >> 3;

    const f16x8* wsf = (const f16x8*)ws;
    const f16x4* wsq = (const f16x4*)(ws + 84 * 512);   // 16x16x16 B-frags

    // ---- permanently-held state: h1 bias + tail weights (all lanes) ----
    f32x4 bl1v0 = ((const f32x4*)bl1)[h],      bl1v1 = ((const f32x4*)bl1)[4 + h];
    f32x4 bl1v2 = ((const f32x4*)bl1)[8 + h],  bl1v3 = ((const f32x4*)bl1)[12 + h];
    const f16x4* wl2p = wsq + 16 * 64 + lane;
    f16x4 l200 = wl2p[0],   l201 = wl2p[64];
    f16x4 l210 = wl2p[128], l211 = wl2p[192];
    f16x4 l220 = wl2p[256], l221 = wl2p[320];
    f16x4 l230 = wl2p[384], l231 = wl2p[448];
    float c0 = bl2[m15], c1 = bl2[m15 + 16];
    float w30 = Wl3[m15], w31 = Wl3[m15 + 16];
    const float bl3s = bl3[0];

    char* wbase = smem + wid * 10240;     // wave-private, never shared
    char* Albuf = wbase;                  // 2048 B (channel time-shared)
    char* xbuf  = wbase + 2048;           // 8192 B (channel time-shared)

    const int rxor = ((m15 >> 1) & 3) << 4;
    const bool bsel = ((h >> 1) == r8);    // s3 B-frag block-diag gate
    const int  hlow = h & 1;               // s3 B-frag row-half select
    f32x4 zero4 = {0.0f, 0.0f, 0.0f, 0.0f};
    f16x4 zf4 = {};

    // this wave's batch range
    long b0 = (long)(blockIdx.x * 2 + wid) * (16 * TILES);

    // current-channel weight registers (ONE set live at a time)
    f16x8 W10, W11, W12, W13;
    f16x4 K00, K01, K10, K11, K20, K21, K30, K31;
    f32x4 B10, B11, B12, B13, B20, B21;

    // ---- prefetch adj for (it=0, c=0) ----
    f32x4 pf0, pf1, pf2, pf3;
    {
        const f32x4* rp0 = (const f32x4*)(adj + (b0 + (lane >> 3)) * 128 + (lane & 7) * 8);
        pf0 = rp0[0]; pf1 = rp0[1];
        const f32x4* rp1 = (const f32x4*)(adj + (b0 + 8 + (lane >> 3)) * 128 + (lane & 7) * 8);
        pf2 = rp1[0]; pf3 = rp1[1];
    }

    #pragma unroll 1
    for (int it = 0; it < TILES; ++it, b0 += 16) {
        // h1 accumulator, bias-seeded; both channels accumulate into it
        f32x4 a40 = bl1v0, a41 = bl1v1, a42 = bl1v2, a43 = bl1v3;

        #pragma unroll 1
        for (int cc = 0; cc < 2; ++cc) {
            // ---- reload this channel's weights (14 VMEM, L1-hot) ----
            {
                const f16x8* w1p = wsf + (64 + cc * 4) * 64 + lane;
                W10 = w1p[0]; W11 = w1p[64]; W12 = w1p[128]; W13 = w1p[192];
                const f16x4* w2p = wsq + (cc * 8) * 64 + lane;
                K00 = w2p[0];   K01 = w2p[64];
                K10 = w2p[128]; K11 = w2p[192];
                K20 = w2p[256]; K21 = w2p[320];
                K30 = w2p[384]; K31 = w2p[448];
                const f32x4* b1p = (const f32x4*)(cc ? bn1 : bp1);
                B10 = b1p[h]; B11 = b1p[4 + h]; B12 = b1p[8 + h]; B13 = b1p[12 + h];
                const f32x4* b2p = (const f32x4*)(cc ? bn2 : bp2);
                B20 = b2p[h]; B21 = b2p[4 + h];
            }

            // ---- Phase A: normalize prefetched rows, stage to Albuf ----
            {
                float s = ((pf0[0] + pf0[1]) + (pf0[2] + pf0[3])) + ((pf1[0] + pf1[1]) + (pf1[2] + pf1[3]));
                float rv = (s > 0.0f) ? __builtin_amdgcn_rcpf(s) : 0.0f;
                u32x4 row = { pkrtz(pf0[0] * rv, pf0[1] * rv), pkrtz(pf0[2] * rv, pf0[3] * rv),
                              pkrtz(pf1[0] * rv, pf1[1] * rv), pkrtz(pf1[2] * rv, pf1[3] * rv) };
                *(u32x4*)(Albuf + lane * 16) = row;
            }
            {
                float s = ((pf2[0] + pf2[1]) + (pf2[2] + pf2[3])) + ((pf3[0] + pf3[1]) + (pf3[2] + pf3[3]));
                float rv = (s > 0.0f) ? __builtin_amdgcn_rcpf(s) : 0.0f;
                u32x4 row = { pkrtz(pf2[0] * rv, pf2[1] * rv), pkrtz(pf2[2] * rv, pf2[3] * rv),
                              pkrtz(pf3[0] * rv, pf3[1] * rv), pkrtz(pf3[2] * rv, pf3[3] * rv) };
                *(u32x4*)(Albuf + (64 + lane) * 16) = row;
            }

            // ---- issue prefetch for the NEXT (tile,channel) step ----
            {
                const int  nc = cc ^ 1;
                const long nb = cc ? (b0 + 16) : b0;
                if (cc == 0 || it + 1 < TILES) {
                    const f32x4* rp0 = (const f32x4*)(adj + (nb + (lane >> 3)) * 128 + nc * 64 + (lane & 7) * 8);
                    pf0 = rp0[0]; pf1 = rp0[1];
                    const f32x4* rp1 = (const f32x4*)(adj + (nb + 8 + (lane >> 3)) * 128 + nc * 64 + (lane & 7) * 8);
                    pf2 = rp1[0]; pf3 = rp1[1];
                }
            }

            // ---- Phase B: fused GCN over t=0..7 ----
            #pragma unroll 2
            for (int t = 0; t < 8; ++t) {
                f16x8 arow = *(const f16x8*)(Albuf + (((2 * t + r8) * 8 + i7) << 4));

                // s1: z^T = W1^T @ A^T + b1 (16x16x32, K=8 pad)
                f32x4 z0 = MFMA32(W10, arow, B10);
                f32x4 z1 = MFMA32(W11, arow, B11);
                f32x4 z2 = MFMA32(W12, arow, B12);
                f32x4 z3 = MFMA32(W13, arow, B13);

                // s1 -> s2: register pack+leaky (packed f16 math)
                f16x4 x0 = lk_pk4(z0), x1 = lk_pk4(z1), x2 = lk_pk4(z2), x3 = lk_pk4(z3);

                // s2: y_nt = sum_kb x1 @ W2 (two 4-chains of 16x16x16)
                f32x4 y0 = MFMA16(x0, K00, zero4);
                f32x4 y1 = MFMA16(x0, K01, zero4);
                y0 = MFMA16(x1, K10, y0);
                y1 = MFMA16(x1, K11, y1);
                y0 = MFMA16(x2, K20, y0);
                y1 = MFMA16(x2, K21, y1);
                y0 = MFMA16(x3, K30, y0);
                y1 = MFMA16(x3, K31, y1);

                // s2 -> s3: register pkrtz; B-frag from arow select (block-diag)
                f16x4 pa0 = pk4(y0), pa1 = pk4(y1);
                u32x4 ar = __builtin_bit_cast(u32x4, arow);
                f16x4 halfa = __builtin_bit_cast(f16x4,
                    hlow ? (u32x2){ar[2], ar[3]} : (u32x2){ar[0], ar[1]});
                f16x4 bfra = bsel ? halfa : zf4;

                // s3: x2^T = y^T @ BD_A^T + b2 (16x16x16, K=16 exact)
                f32x4 x2a = MFMA16(pa0, bfra, B20);
                f32x4 x2b = MFMA16(pa1, bfra, B21);

                // leaky+pack + swizzled xbuf writes; slot = i7, n = 2t+r8
                const int lga = h >> 1;
                const int lgb = lga ^ 2;
                char* fb = xbuf + (i7 << 10);
                int wx = ((t & 3) ^ i7) << 4;
                int basew = ((2 * t + r8) << 6) + ((h & 1) << 3);
                st_lk4(fb + ((basew + lga * 16) ^ wx), x2a);
                st_lk4(fb + ((basew + lgb * 16) ^ wx), x2b);
            }

            // ---- Phase C: h1 partial += Wl1^T[k-half cc] @ x^T (K=256) ----
            __builtin_amdgcn_s_setprio(1);
            #pragma unroll 4
            for (int k8 = 0; k8 < 8; ++k8) {
                int xr = rxor ^ (k8 << 4);
                f16x8 xf = *(const f16x8*)(xbuf + (k8 << 10) + ((m15 * 64 + h * 16) ^ xr));
                const f16x8* wl = wsf + (cc * 8 + k8) * 64 + lane;
                a40 = MFMA32(wl[0],    xf, a40);
                a41 = MFMA32(wl[1024], xf, a41);
                a42 = MFMA32(wl[2048], xf, a42);
                a43 = MFMA32(wl[3072], xf, a43);
            }
            __builtin_amdgcn_s_setprio(0);
        }

        // ---- Phase D: register pack+leaky of h1 (A-frags for E) ----
        f16x4 pd0 = lk_pk4(a40), pd1 = lk_pk4(a41);
        f16x4 pd2 = lk_pk4(a42), pd3 = lk_pk4(a43);

        // ---- Phase E: h2 = h1 @ Wl2 + bl2 (4-chain 16x16x16 per nt) ----
        f32x4 a50 = {c0, c0, c0, c0};
        f32x4 a51 = {c1, c1, c1, c1};
        a50 = MFMA16(pd0, l200, a50);
        a51 = MFMA16(pd0, l201, a51);
        a50 = MFMA16(pd1, l210, a50);
        a51 = MFMA16(pd1, l211, a51);
        a50 = MFMA16(pd2, l220, a50);
        a51 = MFMA16(pd2, l221, a51);
        a50 = MFMA16(pd3, l230, a50);
        a51 = MFMA16(pd3, l231, a51);

        // ---- Phase F: out[b=4h+r] = sum_l2 leaky(h2) Wl3 + bl3 ----
        #pragma unroll
        for (int r = 0; r < 4; ++r) {
            float acc = leaky(a50[r]) * w30 + leaky(a51[r]) * w31;
            acc += __shfl_xor(acc, 1);
            acc += __shfl_xor(acc, 2);
            acc += __shfl_xor(acc, 4);
            acc += __shfl_xor(acc, 8);
            if (m15 == 0) out[b0 + h * 4 + r] = acc + bl3s;
        }
    }
}

extern "C" void kernel_launch(void* const* d_in, const int* in_sizes, int n_in,
                              void* d_out, int out_size, void* d_ws, size_t ws_size,
                              hipStream_t stream)
{
    const float* adj  = (const float*)d_in[0];
    const float* Wp1  = (const float*)d_in[1];
    const float* bp1  = (const float*)d_in[2];
    const float* Wp2  = (const float*)d_in[3];
    const float* bp2  = (const float*)d_in[4];
    const float* Wn1  = (const float*)d_in[5];
    const float* bn1  = (const float*)d_in[6];
    const float* Wn2  = (const float*)d_in[7];
    const float* bn2  = (const float*)d_in[8];
    const float* Wl1  = (const float*)d_in[9];
    const float* bl1  = (const float*)d_in[10];
    const float* Wl2  = (const float*)d_in[11];
    const float* bl2  = (const float*)d_in[12];
    const float* Wl3  = (const float*)d_in[13];
    const float* bl3  = (const float*)d_in[14];
    f16* ws = (f16*)d_ws;
    float* out = (float*)d_out;

    // 84*512 + 24*256 = 49152 f16; 192 blocks x 256 threads
    hipLaunchKernelGGL(disc_prepack, dim3(192), dim3(256), 0, stream,
                       Wp1, Wp2, Wn1, Wn2, Wl1, Wl2, ws);

    const int ldsBytes = 20480;  // 2 waves x (Albuf 2K + xbuf 8K), private
    hipFuncSetAttribute(reinterpret_cast<const void*>(disc_main),
                        hipFuncAttributeMaxDynamicSharedMemorySize, ldsBytes);
    hipLaunchKernelGGL(disc_main, dim3(8192 / (2 * TILES)), dim3(128), ldsBytes, stream,
                       adj, bp1, bp2, bn1, bn2, bl1, bl2, bl3, Wl3, ws, out);
}